// Round 1
// baseline (230.635 us; speedup 1.0000x reference)
//
#include <hip/hip_runtime.h>
#include <hip/hip_bf16.h>

// FullAttention fwd (no dropout), B=4 L=S=2048 H=8 E=D=64, fp32 in/out,
// bf16 MFMA internal. Flash-attention: one block = one (b,h) x 64 Q rows,
// 4 waves x 16 rows, iterate S in 64-wide tiles.

#define BNUM 4
#define LLEN 2048
#define SLEN 2048
#define HNUM 8
#define EDIM 64
#define BM 64
#define BN 64
#define LDP 72   // padded LDS row (shorts): 144B = 16B-aligned rows, breaks pow2 stride

typedef __attribute__((ext_vector_type(8))) short bf16x8;  // 8 bf16 = 4 VGPRs
typedef __attribute__((ext_vector_type(4))) float f32x4;

__device__ __forceinline__ short f2bf(float f) {
    union { __hip_bfloat16 b; short s; } u;
    u.b = __float2bfloat16(f);
    return u.s;
}

__global__ __launch_bounds__(256)
void fa_fwd(const float* __restrict__ Qg, const float* __restrict__ Kg,
            const float* __restrict__ Vg, float* __restrict__ Og)
{
    const int tid  = threadIdx.x;
    const int wave = tid >> 6;
    const int lane = tid & 63;
    const int m    = lane & 15;   // MFMA row (A) / col (B,C)
    const int quad = lane >> 4;   // MFMA k-group / row-group

    const int qblk = blockIdx.x;
    const int h    = blockIdx.y;
    const int b    = blockIdx.z;

    __shared__ short sK[BN][LDP];       // K tile, bf16, [s][e]
    __shared__ short sVt[EDIM][LDP];    // V tile transposed, bf16, [d][s]
    __shared__ short sP[4][16][LDP];    // per-wave P buffer, [q][s]

    const int rs = HNUM * EDIM; // 512 floats between consecutive l/s rows
    const float* Qb = Qg + ((size_t)(b * LLEN + qblk * BM) * HNUM + h) * EDIM;
    const float* Kb = Kg + (size_t)b * SLEN * rs + (size_t)h * EDIM;
    const float* Vb = Vg + (size_t)b * SLEN * rs + (size_t)h * EDIM;
    float*       Ob = Og + ((size_t)(b * LLEN + qblk * BM) * HNUM + h) * EDIM;

    // ---- Q fragments (A layout: row m = lane&15, k = quad*8+j), bf16, registers ----
    bf16x8 qfrag[2];
    {
        const float* qrow = Qb + (size_t)(wave * 16 + m) * rs + quad * 8;
        #pragma unroll
        for (int kb = 0; kb < 2; ++kb) {
            #pragma unroll
            for (int j = 0; j < 8; ++j) qfrag[kb][j] = f2bf(qrow[kb * 32 + j]);
        }
    }

    const float cexp = 0.125f * 1.4426950408889634f; // (1/sqrt(64)) * log2(e)

    float mstate[4] = {-INFINITY, -INFINITY, -INFINITY, -INFINITY};
    float lstate[4] = {0.f, 0.f, 0.f, 0.f};
    f32x4 oacc[4] = {{0.f,0.f,0.f,0.f},{0.f,0.f,0.f,0.f},
                     {0.f,0.f,0.f,0.f},{0.f,0.f,0.f,0.f}};

    const int srow = tid >> 2;        // staging: 4 threads per tile row
    const int scol = (tid & 3) * 16;  // 16 floats each

    for (int s0 = 0; s0 < SLEN; s0 += BN) {
        // ---- stage K (row-major) and V (transposed) to LDS as bf16 ----
        {
            const float* ks = Kb + (size_t)(s0 + srow) * rs + scol;
            const float* vs = Vb + (size_t)(s0 + srow) * rs + scol;
            #pragma unroll
            for (int half = 0; half < 2; ++half) {
                float4 x0 = *(const float4*)(ks + half * 8);
                float4 x1 = *(const float4*)(ks + half * 8 + 4);
                bf16x8 kv;
                kv[0]=f2bf(x0.x); kv[1]=f2bf(x0.y); kv[2]=f2bf(x0.z); kv[3]=f2bf(x0.w);
                kv[4]=f2bf(x1.x); kv[5]=f2bf(x1.y); kv[6]=f2bf(x1.z); kv[7]=f2bf(x1.w);
                *(bf16x8*)&sK[srow][scol + half * 8] = kv;
            }
            #pragma unroll
            for (int half = 0; half < 2; ++half) {
                float4 x0 = *(const float4*)(vs + half * 8);
                float4 x1 = *(const float4*)(vs + half * 8 + 4);
                float vv[8] = {x0.x,x0.y,x0.z,x0.w,x1.x,x1.y,x1.z,x1.w};
                #pragma unroll
                for (int j = 0; j < 8; ++j)
                    sVt[scol + half * 8 + j][srow] = f2bf(vv[j]);
            }
        }
        __syncthreads();

        // ---- S = Q K^T  (4 col-tiles of 16, K-dim 64 = 2 MFMAs each) ----
        // B layout: lane holds B[k=quad*8+j][n=m] = K[s=t*16+m][e=kb*32+quad*8+j]
        f32x4 sacc[4];
        #pragma unroll
        for (int t = 0; t < 4; ++t) {
            f32x4 acc = {0.f, 0.f, 0.f, 0.f};
            #pragma unroll
            for (int kb = 0; kb < 2; ++kb) {
                bf16x8 kf = *(const bf16x8*)&sK[t * 16 + m][kb * 32 + quad * 8];
                acc = __builtin_amdgcn_mfma_f32_16x16x32_bf16(qfrag[kb], kf, acc, 0, 0, 0);
            }
            sacc[t] = acc;
        }

        // ---- online softmax (C layout: row = quad*4+r, col = t*16+m) ----
        float alpha[4];
        #pragma unroll
        for (int r = 0; r < 4; ++r) {
            float mx = fmaxf(fmaxf(sacc[0][r], sacc[1][r]),
                             fmaxf(sacc[2][r], sacc[3][r]));
            mx = fmaxf(mx, __shfl_xor(mx, 1));
            mx = fmaxf(mx, __shfl_xor(mx, 2));
            mx = fmaxf(mx, __shfl_xor(mx, 4));
            mx = fmaxf(mx, __shfl_xor(mx, 8));
            float mnew = fmaxf(mstate[r], mx);
            alpha[r] = exp2f((mstate[r] - mnew) * cexp);
            mstate[r] = mnew;
            float rsum = 0.f;
            #pragma unroll
            for (int t = 0; t < 4; ++t) {
                float p = exp2f((sacc[t][r] - mnew) * cexp);
                sacc[t][r] = p;
                rsum += p;
            }
            rsum += __shfl_xor(rsum, 1);
            rsum += __shfl_xor(rsum, 2);
            rsum += __shfl_xor(rsum, 4);
            rsum += __shfl_xor(rsum, 8);
            lstate[r] = lstate[r] * alpha[r] + rsum;
        }

        // rescale O accumulator
        #pragma unroll
        for (int t = 0; t < 4; ++t)
            #pragma unroll
            for (int r = 0; r < 4; ++r)
                oacc[t][r] *= alpha[r];

        // ---- P: C layout -> LDS -> A layout (wave-private buffer, no barrier) ----
        #pragma unroll
        for (int t = 0; t < 4; ++t)
            #pragma unroll
            for (int r = 0; r < 4; ++r)
                sP[wave][quad * 4 + r][t * 16 + m] = f2bf(sacc[t][r]);

        bf16x8 pf[2];
        pf[0] = *(const bf16x8*)&sP[wave][m][quad * 8];
        pf[1] = *(const bf16x8*)&sP[wave][m][32 + quad * 8];

        // ---- O += P V  (B layout from sVt: V[s=kb*32+quad*8+j][d=t*16+m]) ----
        #pragma unroll
        for (int t = 0; t < 4; ++t) {
            #pragma unroll
            for (int kb = 0; kb < 2; ++kb) {
                bf16x8 vf = *(const bf16x8*)&sVt[t * 16 + m][kb * 32 + quad * 8];
                oacc[t] = __builtin_amdgcn_mfma_f32_16x16x32_bf16(pf[kb], vf, oacc[t], 0, 0, 0);
            }
        }
        __syncthreads();  // protect sK/sVt before next stage
    }

    // ---- epilogue: O / l, fp32 stores ----
    #pragma unroll
    for (int r = 0; r < 4; ++r) {
        float inv = 1.0f / lstate[r];
        float* orow = Ob + (size_t)(wave * 16 + quad * 4 + r) * rs;
        #pragma unroll
        for (int t = 0; t < 4; ++t)
            orow[t * 16 + m] = oacc[t][r] * inv;
    }
}

extern "C" void kernel_launch(void* const* d_in, const int* in_sizes, int n_in,
                              void* d_out, int out_size, void* d_ws, size_t ws_size,
                              hipStream_t stream) {
    const float* Q = (const float*)d_in[0];
    const float* K = (const float*)d_in[1];
    const float* V = (const float*)d_in[2];
    float* O = (float*)d_out;
    dim3 grid(LLEN / BM, HNUM, BNUM);
    fa_fwd<<<grid, dim3(256), 0, stream>>>(Q, K, V, O);
}